// Round 1
// baseline (974.314 us; speedup 1.0000x reference)
//
#include <hip/hip_runtime.h>
#include <math.h>

// ---------------- degree count ----------------
__global__ void deg_count_kernel(const int* __restrict__ row, int* __restrict__ degi, int E) {
    int g = blockIdx.x * blockDim.x + threadIdx.x;
    if (g < E) atomicAdd(&degi[row[g]], 1);
}

// ---------------- per-node GSO coefficients ----------------
// coeff[n] = {m2_1*pow(d1,e2_1), pow(d1,e3_1), m2_2*pow(d2,e2_2), pow(d2,e3_2)}
// wself[n] = sum over both GSOs of m1*pow(d,e1) + m2*pow(d,e2)*pow(d,e3) + m3
__device__ __forceinline__ float pow_z(float d, float e) {
    float p = powf(d, e);
    return isinf(p) ? 0.0f : p;   // reference zeroes inf from 0**negative
}

__global__ void node_coeff_kernel(const int* __restrict__ degi,
                                  const float* __restrict__ p1, const float* __restrict__ p2,
                                  float4* __restrict__ coeff, float* __restrict__ wself, int N) {
    int g = blockIdx.x * blockDim.x + threadIdx.x;
    if (g >= N) return;
    float deg = (float)degi[g];
    float m1a = p1[0], m2a = p1[1], m3a = p1[2], e1a = p1[3], e2a = p1[4], e3a = p1[5], aa = p1[6];
    float m1b = p2[0], m2b = p2[1], m3b = p2[2], e1b = p2[3], e2b = p2[4], e3b = p2[5], ab = p2[6];
    float d1 = deg + aa, d2 = deg + ab;
    float pa1 = pow_z(d1, e1a), pa2 = pow_z(d1, e2a), pa3 = pow_z(d1, e3a);
    float pb1 = pow_z(d2, e1b), pb2 = pow_z(d2, e2b), pb3 = pow_z(d2, e3b);
    coeff[g] = make_float4(m2a * pa2, pa3, m2b * pb2, pb3);
    wself[g] = m1a * pa1 + m2a * pa2 * pa3 + m3a
             + m1b * pb1 + m2b * pb2 * pb3 + m3b;
}

// ---------------- exclusive scan of degrees -> rowptr ----------------
// K1: per-block (1024 elems) inclusive scan written to rowptr[g+1]; block total to blocksum
__global__ void scan_block_kernel(const int* __restrict__ degi, int* __restrict__ rowptr,
                                  int* __restrict__ blocksum, int n) {
    __shared__ int sums[256];
    int tid = threadIdx.x;
    int base = blockIdx.x * 1024 + tid * 4;
    int d0 = (base + 0 < n) ? degi[base + 0] : 0;
    int d1 = (base + 1 < n) ? degi[base + 1] : 0;
    int d2 = (base + 2 < n) ? degi[base + 2] : 0;
    int d3 = (base + 3 < n) ? degi[base + 3] : 0;
    int s0 = d0, s1 = s0 + d1, s2 = s1 + d2, s3 = s2 + d3;
    sums[tid] = s3;
    __syncthreads();
    for (int off = 1; off < 256; off <<= 1) {
        int v = (tid >= off) ? sums[tid - off] : 0;
        __syncthreads();
        sums[tid] += v;
        __syncthreads();
    }
    int excl = sums[tid] - s3;
    if (base + 0 < n) rowptr[base + 1] = excl + s0;
    if (base + 1 < n) rowptr[base + 2] = excl + s1;
    if (base + 2 < n) rowptr[base + 3] = excl + s2;
    if (base + 3 < n) rowptr[base + 4] = excl + s3;
    if (tid == 255) blocksum[blockIdx.x] = sums[255];
}

// K2: single block exclusive scan over block sums (NBLK <= 128)
__global__ void scan_tops_kernel(const int* __restrict__ blocksum, int* __restrict__ blockoff, int nb) {
    __shared__ int s[128];
    int tid = threadIdx.x;
    int v = (tid < nb) ? blocksum[tid] : 0;
    s[tid] = v;
    __syncthreads();
    for (int off = 1; off < 128; off <<= 1) {
        int u = (tid >= off) ? s[tid - off] : 0;
        __syncthreads();
        s[tid] += u;
        __syncthreads();
    }
    if (tid < nb) blockoff[tid] = s[tid] - v;
}

// K3: add block offsets, set rowptr[0]
__global__ void scan_add_kernel(int* __restrict__ rowptr, const int* __restrict__ blockoff, int n) {
    int g = blockIdx.x * blockDim.x + threadIdx.x;
    if (g == 0) rowptr[0] = 0;
    if (g < n) rowptr[g + 1] += blockoff[g >> 10];
}

// ---------------- CSR fill + edge weights ----------------
__global__ void fill_edges_kernel(const int* __restrict__ row, const int* __restrict__ col,
                                  const int* __restrict__ rowptr, int* __restrict__ cursor,
                                  const float4* __restrict__ coeff, int* __restrict__ colidx,
                                  float* __restrict__ wedge, int E) {
    int g = blockIdx.x * blockDim.x + threadIdx.x;
    if (g >= E) return;
    int r = row[g], c = col[g];
    int pos = rowptr[r] + atomicAdd(&cursor[r], 1);
    float4 cr = coeff[r], cc = coeff[c];
    colidx[pos] = c;
    wedge[pos] = cr.x * cc.y + cr.z * cc.w;
}

// ---------------- dense GEMM: A[n x 128] @ W[128 x TN] -> C[n x TN] ----------------
// 256 threads; per-thread 8x8 register tile; K staged in chunks of 32 through LDS.
template<int TN>
__global__ __launch_bounds__(256) void gemm_k128(const float* __restrict__ A,
                                                 const float* __restrict__ W,
                                                 float* __restrict__ C, int n) {
    constexpr int CT = TN / 8;        // col-threads (16 for TN=128, 8 for TN=64)
    constexpr int RT = 256 / CT;      // row-threads (16 / 32)
    constexpr int TM = RT * 8;        // rows per block (128 / 256)
    constexpr int KC = 32;
    constexpr int XPAD = TM + 4;      // keep stride multiple of 4 for float4 LDS reads
    __shared__ __align__(16) float Xst[KC][XPAD]; // transposed: Xst[k][r]
    __shared__ __align__(16) float Ws[KC][TN];

    int tid = threadIdx.x;
    int tc = tid % CT, tr = tid / CT;
    int r0 = tr * 8, j0 = tc * 8;
    int rowbase = blockIdx.x * TM;

    float acc[8][8];
#pragma unroll
    for (int i = 0; i < 8; ++i)
#pragma unroll
        for (int j = 0; j < 8; ++j) acc[i][j] = 0.0f;

    for (int kc = 0; kc < 128; kc += KC) {
        __syncthreads();
        // stage X chunk (transposed)
        for (int idx = tid; idx < TM * KC; idx += 256) {
            int r = idx >> 5, k = idx & 31;
            int rr = rowbase + r;
            Xst[k][r] = (rr < n) ? A[(size_t)rr * 128 + kc + k] : 0.0f;
        }
        // stage W chunk
        for (int idx = tid; idx < KC * TN; idx += 256) {
            int k = idx / TN, c = idx % TN;
            Ws[k][c] = W[(size_t)(kc + k) * TN + c];
        }
        __syncthreads();
#pragma unroll 4
        for (int k = 0; k < KC; ++k) {
            float4 x0 = *(const float4*)&Xst[k][r0];
            float4 x1 = *(const float4*)&Xst[k][r0 + 4];
            float4 w0 = *(const float4*)&Ws[k][j0];
            float4 w1 = *(const float4*)&Ws[k][j0 + 4];
            float xs[8] = {x0.x, x0.y, x0.z, x0.w, x1.x, x1.y, x1.z, x1.w};
            float wv[8] = {w0.x, w0.y, w0.z, w0.w, w1.x, w1.y, w1.z, w1.w};
#pragma unroll
            for (int i = 0; i < 8; ++i)
#pragma unroll
                for (int j = 0; j < 8; ++j) acc[i][j] += xs[i] * wv[j];
        }
    }
#pragma unroll
    for (int i = 0; i < 8; ++i) {
        int rr = rowbase + r0 + i;
        if (rr < n) {
            float4 o0 = make_float4(acc[i][0], acc[i][1], acc[i][2], acc[i][3]);
            float4 o1 = make_float4(acc[i][4], acc[i][5], acc[i][6], acc[i][7]);
            *(float4*)&C[(size_t)rr * TN + j0] = o0;
            *(float4*)&C[(size_t)rr * TN + j0 + 4] = o1;
        }
    }
}

// ---------------- CSR aggregation: out = agg + wself*H + b (, relu) ----------------
template<int D, bool RELU>
__global__ __launch_bounds__(256) void agg_kernel(const float* __restrict__ H,
        const int* __restrict__ rowptr, const int* __restrict__ colidx,
        const float* __restrict__ wedge, const float* __restrict__ wself,
        const float* __restrict__ bias, float* __restrict__ out, int n) {
    constexpr int NPB = 256 / D;
    int node = blockIdx.x * NPB + threadIdx.x / D;
    int d = threadIdx.x % D;
    if (node >= n) return;
    int start = rowptr[node], end = rowptr[node + 1];
    float acc = wself[node] * H[(size_t)node * D + d];
    int cn = 0; float wn = 0.0f;
    if (start < end) { cn = colidx[start]; wn = wedge[start]; }
    for (int e = start; e < end; ++e) {
        int c = cn; float w = wn;
        if (e + 1 < end) { cn = colidx[e + 1]; wn = wedge[e + 1]; }  // prefetch next edge
        acc += w * H[(size_t)c * D + d];
    }
    float v = acc + bias[d];
    out[(size_t)node * D + d] = RELU ? fmaxf(v, 0.0f) : v;
}

// ---------------- launch ----------------
extern "C" void kernel_launch(void* const* d_in, const int* in_sizes, int n_in,
                              void* d_out, int out_size, void* d_ws, size_t ws_size,
                              hipStream_t stream) {
    const float* x  = (const float*)d_in[0];
    const int*   ei = (const int*)d_in[1];
    const float* W1 = (const float*)d_in[2];
    const float* b1 = (const float*)d_in[3];
    const float* W2 = (const float*)d_in[4];
    const float* b2 = (const float*)d_in[5];
    const float* W3 = (const float*)d_in[6];
    const float* b3 = (const float*)d_in[7];
    const float* p1 = (const float*)d_in[8];
    const float* p2 = (const float*)d_in[9];

    const int N = in_sizes[0] / 128;
    const int E = in_sizes[1] / 2;
    const int* row = ei;
    const int* col = ei + E;

    char* p = (char*)d_ws;
    auto alloc = [&](size_t bytes) -> void* {
        void* q = (void*)p;
        p += (bytes + 255) & ~(size_t)255;
        return q;
    };
    int*    degi     = (int*)alloc((size_t)N * 4);
    int*    cursor   = (int*)alloc((size_t)N * 4);       // contiguous with degi for one memset
    int*    rowptr   = (int*)alloc((size_t)(N + 1) * 4);
    const int NBLK   = (N + 1023) / 1024;                // 98 for N=100000 (<=128 required)
    int*    blocksum = (int*)alloc((size_t)NBLK * 4);
    int*    blockoff = (int*)alloc((size_t)NBLK * 4);
    float4* coeff    = (float4*)alloc((size_t)N * 16);
    float*  wself    = (float*)alloc((size_t)N * 4);
    int*    colidx   = (int*)alloc((size_t)E * 4);
    float*  wedge    = (float*)alloc((size_t)E * 4);
    float*  bufA     = (float*)alloc((size_t)N * 128 * 4);
    float*  bufB     = (float*)alloc((size_t)N * 128 * 4);
    (void)ws_size; (void)n_in;

    // zero degi + cursor (contiguous region)
    size_t zero_bytes = (size_t)((char*)rowptr - (char*)degi);
    hipMemsetAsync(degi, 0, zero_bytes, stream);

    deg_count_kernel<<<(E + 255) / 256, 256, 0, stream>>>(row, degi, E);
    node_coeff_kernel<<<(N + 255) / 256, 256, 0, stream>>>(degi, p1, p2, coeff, wself, N);
    scan_block_kernel<<<NBLK, 256, 0, stream>>>(degi, rowptr, blocksum, N);
    scan_tops_kernel<<<1, 128, 0, stream>>>(blocksum, blockoff, NBLK);
    scan_add_kernel<<<(N + 255) / 256, 256, 0, stream>>>(rowptr, blockoff, N);
    fill_edges_kernel<<<(E + 255) / 256, 256, 0, stream>>>(row, col, rowptr, cursor, coeff,
                                                           colidx, wedge, E);

    float* out = (float*)d_out;
    // layer 1: H = x @ W1 ; B = relu(agg(H) + wself*H + b1)
    gemm_k128<128><<<dim3((N + 127) / 128), 256, 0, stream>>>(x, W1, bufA, N);
    agg_kernel<128, true><<<(N + 1) / 2, 256, 0, stream>>>(bufA, rowptr, colidx, wedge, wself, b1, bufB, N);
    // layer 2
    gemm_k128<128><<<dim3((N + 127) / 128), 256, 0, stream>>>(bufB, W2, bufA, N);
    agg_kernel<128, true><<<(N + 1) / 2, 256, 0, stream>>>(bufA, rowptr, colidx, wedge, wself, b2, bufB, N);
    // layer 3 (D_OUT=64, no relu)
    gemm_k128<64><<<dim3((N + 255) / 256), 256, 0, stream>>>(bufB, W3, bufA, N);
    agg_kernel<64, false><<<(N + 3) / 4, 256, 0, stream>>>(bufA, rowptr, colidx, wedge, wself, b3, out, N);
}

// Round 2
// 660.380 us; speedup vs baseline: 1.4754x; 1.4754x over previous
//
#include <hip/hip_runtime.h>
#include <hip/hip_fp16.h>
#include <math.h>

// ---------------- degree count ----------------
__global__ void deg_count_kernel(const int* __restrict__ row, int* __restrict__ degi, int E) {
    int g = blockIdx.x * blockDim.x + threadIdx.x;
    if (g < E) atomicAdd(&degi[row[g]], 1);
}

// ---------------- per-node GSO coefficients ----------------
__device__ __forceinline__ float pow_z(float d, float e) {
    float p = powf(d, e);
    return isinf(p) ? 0.0f : p;   // reference zeroes inf from 0**negative
}

__global__ void node_coeff_kernel(const int* __restrict__ degi,
                                  const float* __restrict__ p1, const float* __restrict__ p2,
                                  float4* __restrict__ coeff, float* __restrict__ wself, int N) {
    int g = blockIdx.x * blockDim.x + threadIdx.x;
    if (g >= N) return;
    float deg = (float)degi[g];
    float m1a = p1[0], m2a = p1[1], m3a = p1[2], e1a = p1[3], e2a = p1[4], e3a = p1[5], aa = p1[6];
    float m1b = p2[0], m2b = p2[1], m3b = p2[2], e1b = p2[3], e2b = p2[4], e3b = p2[5], ab = p2[6];
    float d1 = deg + aa, d2 = deg + ab;
    float pa1 = pow_z(d1, e1a), pa2 = pow_z(d1, e2a), pa3 = pow_z(d1, e3a);
    float pb1 = pow_z(d2, e1b), pb2 = pow_z(d2, e2b), pb3 = pow_z(d2, e3b);
    coeff[g] = make_float4(m2a * pa2, pa3, m2b * pb2, pb3);
    wself[g] = m1a * pa1 + m2a * pa2 * pa3 + m3a
             + m1b * pb1 + m2b * pb2 * pb3 + m3b;
}

// ---------------- exclusive scan of degrees -> rowptr ----------------
__global__ void scan_block_kernel(const int* __restrict__ degi, int* __restrict__ rowptr,
                                  int* __restrict__ blocksum, int n) {
    __shared__ int sums[256];
    int tid = threadIdx.x;
    int base = blockIdx.x * 1024 + tid * 4;
    int d0 = (base + 0 < n) ? degi[base + 0] : 0;
    int d1 = (base + 1 < n) ? degi[base + 1] : 0;
    int d2 = (base + 2 < n) ? degi[base + 2] : 0;
    int d3 = (base + 3 < n) ? degi[base + 3] : 0;
    int s0 = d0, s1 = s0 + d1, s2 = s1 + d2, s3 = s2 + d3;
    sums[tid] = s3;
    __syncthreads();
    for (int off = 1; off < 256; off <<= 1) {
        int v = (tid >= off) ? sums[tid - off] : 0;
        __syncthreads();
        sums[tid] += v;
        __syncthreads();
    }
    int excl = sums[tid] - s3;
    if (base + 0 < n) rowptr[base + 1] = excl + s0;
    if (base + 1 < n) rowptr[base + 2] = excl + s1;
    if (base + 2 < n) rowptr[base + 3] = excl + s2;
    if (base + 3 < n) rowptr[base + 4] = excl + s3;
    if (tid == 255) blocksum[blockIdx.x] = sums[255];
}

__global__ void scan_tops_kernel(const int* __restrict__ blocksum, int* __restrict__ blockoff, int nb) {
    __shared__ int s[128];
    int tid = threadIdx.x;
    int v = (tid < nb) ? blocksum[tid] : 0;
    s[tid] = v;
    __syncthreads();
    for (int off = 1; off < 128; off <<= 1) {
        int u = (tid >= off) ? s[tid - off] : 0;
        __syncthreads();
        s[tid] += u;
        __syncthreads();
    }
    if (tid < nb) blockoff[tid] = s[tid] - v;
}

__global__ void scan_add_kernel(int* __restrict__ rowptr, const int* __restrict__ blockoff, int n) {
    int g = blockIdx.x * blockDim.x + threadIdx.x;
    if (g == 0) rowptr[0] = 0;
    if (g < n) rowptr[g + 1] += blockoff[g >> 10];
}

// ---------------- CSR fill + edge weights ----------------
__global__ void fill_edges_kernel(const int* __restrict__ row, const int* __restrict__ col,
                                  const int* __restrict__ rowptr, int* __restrict__ cursor,
                                  const float4* __restrict__ coeff, int* __restrict__ colidx,
                                  float* __restrict__ wedge, int E) {
    int g = blockIdx.x * blockDim.x + threadIdx.x;
    if (g >= E) return;
    int r = row[g], c = col[g];
    int pos = rowptr[r] + atomicAdd(&cursor[r], 1);
    float4 cr = coeff[r], cc = coeff[c];
    colidx[pos] = c;
    wedge[pos] = cr.x * cc.y + cr.z * cc.w;
}

// ---------------- dense GEMM: A[n x 128] @ W[128 x TN] -> Ch[n x TN] (fp16 out) ----
template<int TN>
__global__ __launch_bounds__(256) void gemm_k128(const float* __restrict__ A,
                                                 const float* __restrict__ W,
                                                 __half* __restrict__ Ch, int n) {
    constexpr int CT = TN / 8;        // col-threads (16 for TN=128, 8 for TN=64)
    constexpr int RT = 256 / CT;      // row-threads (16 / 32)
    constexpr int TM = RT * 8;        // rows per block (128 / 256)
    constexpr int KC = 32;
    constexpr int XPAD = TM + 4;      // stride multiple of 4 for float4 LDS reads
    __shared__ __align__(16) float Xst[KC][XPAD]; // transposed: Xst[k][r]
    __shared__ __align__(16) float Ws[KC][TN];

    int tid = threadIdx.x;
    int tc = tid % CT, tr = tid / CT;
    int r0 = tr * 8, j0 = tc * 8;
    int rowbase = blockIdx.x * TM;

    float acc[8][8];
#pragma unroll
    for (int i = 0; i < 8; ++i)
#pragma unroll
        for (int j = 0; j < 8; ++j) acc[i][j] = 0.0f;

    for (int kc = 0; kc < 128; kc += KC) {
        __syncthreads();
        for (int idx = tid; idx < TM * KC; idx += 256) {
            int r = idx >> 5, k = idx & 31;
            int rr = rowbase + r;
            Xst[k][r] = (rr < n) ? A[(size_t)rr * 128 + kc + k] : 0.0f;
        }
        for (int idx = tid; idx < KC * TN; idx += 256) {
            int k = idx / TN, c = idx % TN;
            Ws[k][c] = W[(size_t)(kc + k) * TN + c];
        }
        __syncthreads();
#pragma unroll 4
        for (int k = 0; k < KC; ++k) {
            float4 x0 = *(const float4*)&Xst[k][r0];
            float4 x1 = *(const float4*)&Xst[k][r0 + 4];
            float4 w0 = *(const float4*)&Ws[k][j0];
            float4 w1 = *(const float4*)&Ws[k][j0 + 4];
            float xs[8] = {x0.x, x0.y, x0.z, x0.w, x1.x, x1.y, x1.z, x1.w};
            float wv[8] = {w0.x, w0.y, w0.z, w0.w, w1.x, w1.y, w1.z, w1.w};
#pragma unroll
            for (int i = 0; i < 8; ++i)
#pragma unroll
                for (int j = 0; j < 8; ++j) acc[i][j] += xs[i] * wv[j];
        }
    }
#pragma unroll
    for (int i = 0; i < 8; ++i) {
        int rr = rowbase + r0 + i;
        if (rr < n) {
            __half tmp[8];
#pragma unroll
            for (int j = 0; j < 8; ++j) tmp[j] = __float2half_rn(acc[i][j]);
            *(uint4*)&Ch[(size_t)rr * TN + j0] = *(const uint4*)tmp;
        }
    }
}

// ---------------- CSR aggregation, D=128 (fp16 gather source) ----------------
// One node per wave; lane l holds features [2l, 2l+1] as half2. 4 edges in flight.
__global__ __launch_bounds__(256) void agg128_kernel(const __half2* __restrict__ H,
        const int* __restrict__ rowptr, const int* __restrict__ colidx,
        const float* __restrict__ wedge, const float* __restrict__ wself,
        const float* __restrict__ bias, float* __restrict__ out, int n, int relu) {
    int node = blockIdx.x * 4 + (threadIdx.x >> 6);
    if (node >= n) return;
    int lane = threadIdx.x & 63;
    int start = rowptr[node], end = rowptr[node + 1];
    float ws = wself[node];
    float2 hs = __half22float2(H[(size_t)node * 64 + lane]);
    float ax = ws * hs.x, ay = ws * hs.y;
    int e = start;
    for (; e + 4 <= end; e += 4) {
        int c0 = colidx[e], c1 = colidx[e + 1], c2 = colidx[e + 2], c3 = colidx[e + 3];
        float w0 = wedge[e], w1 = wedge[e + 1], w2 = wedge[e + 2], w3 = wedge[e + 3];
        __half2 h0 = H[(size_t)c0 * 64 + lane];
        __half2 h1 = H[(size_t)c1 * 64 + lane];
        __half2 h2 = H[(size_t)c2 * 64 + lane];
        __half2 h3 = H[(size_t)c3 * 64 + lane];
        float2 f0 = __half22float2(h0), f1 = __half22float2(h1);
        float2 f2 = __half22float2(h2), f3 = __half22float2(h3);
        ax += w0 * f0.x + w1 * f1.x + w2 * f2.x + w3 * f3.x;
        ay += w0 * f0.y + w1 * f1.y + w2 * f2.y + w3 * f3.y;
    }
    for (; e < end; ++e) {
        int c = colidx[e]; float w = wedge[e];
        float2 f = __half22float2(H[(size_t)c * 64 + lane]);
        ax += w * f.x; ay += w * f.y;
    }
    float2 b = *(const float2*)&bias[2 * lane];
    float vx = ax + b.x, vy = ay + b.y;
    if (relu) { vx = fmaxf(vx, 0.0f); vy = fmaxf(vy, 0.0f); }
    *(float2*)&out[(size_t)node * 128 + 2 * lane] = make_float2(vx, vy);
}

// ---------------- CSR aggregation, D=64 (fp16 gather source) ----------------
// One node per wave; lane l holds feature l as half.
__global__ __launch_bounds__(256) void agg64_kernel(const __half* __restrict__ H,
        const int* __restrict__ rowptr, const int* __restrict__ colidx,
        const float* __restrict__ wedge, const float* __restrict__ wself,
        const float* __restrict__ bias, float* __restrict__ out, int n, int relu) {
    int node = blockIdx.x * 4 + (threadIdx.x >> 6);
    if (node >= n) return;
    int lane = threadIdx.x & 63;
    int start = rowptr[node], end = rowptr[node + 1];
    float ws = wself[node];
    float acc = ws * __half2float(H[(size_t)node * 64 + lane]);
    int e = start;
    for (; e + 4 <= end; e += 4) {
        int c0 = colidx[e], c1 = colidx[e + 1], c2 = colidx[e + 2], c3 = colidx[e + 3];
        float w0 = wedge[e], w1 = wedge[e + 1], w2 = wedge[e + 2], w3 = wedge[e + 3];
        float f0 = __half2float(H[(size_t)c0 * 64 + lane]);
        float f1 = __half2float(H[(size_t)c1 * 64 + lane]);
        float f2 = __half2float(H[(size_t)c2 * 64 + lane]);
        float f3 = __half2float(H[(size_t)c3 * 64 + lane]);
        acc += w0 * f0 + w1 * f1 + w2 * f2 + w3 * f3;
    }
    for (; e < end; ++e) {
        acc += wedge[e] * __half2float(H[(size_t)colidx[e] * 64 + lane]);
    }
    float v = acc + bias[lane];
    if (relu) v = fmaxf(v, 0.0f);
    out[(size_t)node * 64 + lane] = v;
}

// ---------------- launch ----------------
extern "C" void kernel_launch(void* const* d_in, const int* in_sizes, int n_in,
                              void* d_out, int out_size, void* d_ws, size_t ws_size,
                              hipStream_t stream) {
    const float* x  = (const float*)d_in[0];
    const int*   ei = (const int*)d_in[1];
    const float* W1 = (const float*)d_in[2];
    const float* b1 = (const float*)d_in[3];
    const float* W2 = (const float*)d_in[4];
    const float* b2 = (const float*)d_in[5];
    const float* W3 = (const float*)d_in[6];
    const float* b3 = (const float*)d_in[7];
    const float* p1 = (const float*)d_in[8];
    const float* p2 = (const float*)d_in[9];

    const int N = in_sizes[0] / 128;
    const int E = in_sizes[1] / 2;
    const int* row = ei;
    const int* col = ei + E;

    char* p = (char*)d_ws;
    auto alloc = [&](size_t bytes) -> void* {
        void* q = (void*)p;
        p += (bytes + 255) & ~(size_t)255;
        return q;
    };
    int*    degi     = (int*)alloc((size_t)N * 4);
    int*    cursor   = (int*)alloc((size_t)N * 4);       // contiguous with degi for one memset
    int*    rowptr   = (int*)alloc((size_t)(N + 1) * 4);
    const int NBLK   = (N + 1023) / 1024;                // 98 for N=100000
    int*    blocksum = (int*)alloc((size_t)NBLK * 4);
    int*    blockoff = (int*)alloc((size_t)NBLK * 4);
    float4* coeff    = (float4*)alloc((size_t)N * 16);
    float*  wself    = (float*)alloc((size_t)N * 4);
    int*    colidx   = (int*)alloc((size_t)E * 4);
    float*  wedge    = (float*)alloc((size_t)E * 4);
    __half* bufH     = (__half*)alloc((size_t)N * 128 * 2);  // fp16 GEMM output (gather source)
    float*  bufAct   = (float*)alloc((size_t)N * 128 * 4);   // fp32 layer activations
    (void)ws_size; (void)n_in;

    size_t zero_bytes = (size_t)((char*)rowptr - (char*)degi);
    hipMemsetAsync(degi, 0, zero_bytes, stream);

    deg_count_kernel<<<(E + 255) / 256, 256, 0, stream>>>(row, degi, E);
    node_coeff_kernel<<<(N + 255) / 256, 256, 0, stream>>>(degi, p1, p2, coeff, wself, N);
    scan_block_kernel<<<NBLK, 256, 0, stream>>>(degi, rowptr, blocksum, N);
    scan_tops_kernel<<<1, 128, 0, stream>>>(blocksum, blockoff, NBLK);
    scan_add_kernel<<<(N + 255) / 256, 256, 0, stream>>>(rowptr, blockoff, N);
    fill_edges_kernel<<<(E + 255) / 256, 256, 0, stream>>>(row, col, rowptr, cursor, coeff,
                                                           colidx, wedge, E);

    float* out = (float*)d_out;
    int aggGrid = (N + 3) / 4;
    // layer 1
    gemm_k128<128><<<dim3((N + 127) / 128), 256, 0, stream>>>(x, W1, bufH, N);
    agg128_kernel<<<aggGrid, 256, 0, stream>>>((const __half2*)bufH, rowptr, colidx, wedge,
                                               wself, b1, bufAct, N, 1);
    // layer 2
    gemm_k128<128><<<dim3((N + 127) / 128), 256, 0, stream>>>(bufAct, W2, bufH, N);
    agg128_kernel<<<aggGrid, 256, 0, stream>>>((const __half2*)bufH, rowptr, colidx, wedge,
                                               wself, b2, bufAct, N, 1);
    // layer 3 (D_OUT=64, no relu)
    gemm_k128<64><<<dim3((N + 255) / 256), 256, 0, stream>>>(bufAct, W3, bufH, N);
    agg64_kernel<<<aggGrid, 256, 0, stream>>>(bufH, rowptr, colidx, wedge,
                                              wself, b3, out, N, 0);
}

// Round 3
// 538.060 us; speedup vs baseline: 1.8108x; 1.2273x over previous
//
#include <hip/hip_runtime.h>
#include <hip/hip_fp16.h>
#include <math.h>
#include <type_traits>

typedef _Float16 half8 __attribute__((ext_vector_type(8)));
typedef float floatx4 __attribute__((ext_vector_type(4)));

// ---------------- degree count ----------------
__global__ void deg_count_kernel(const int* __restrict__ row, int* __restrict__ degi, int E) {
    int g = blockIdx.x * blockDim.x + threadIdx.x;
    if (g < E) atomicAdd(&degi[row[g]], 1);
}

// ---------------- per-node GSO coefficients ----------------
__device__ __forceinline__ float pow_z(float d, float e) {
    float p = powf(d, e);
    return isinf(p) ? 0.0f : p;   // reference zeroes inf from 0**negative
}

__global__ void node_coeff_kernel(const int* __restrict__ degi,
                                  const float* __restrict__ p1, const float* __restrict__ p2,
                                  float4* __restrict__ coeff, float* __restrict__ wself, int N) {
    int g = blockIdx.x * blockDim.x + threadIdx.x;
    if (g >= N) return;
    float deg = (float)degi[g];
    float m1a = p1[0], m2a = p1[1], m3a = p1[2], e1a = p1[3], e2a = p1[4], e3a = p1[5], aa = p1[6];
    float m1b = p2[0], m2b = p2[1], m3b = p2[2], e1b = p2[3], e2b = p2[4], e3b = p2[5], ab = p2[6];
    float d1 = deg + aa, d2 = deg + ab;
    float pa1 = pow_z(d1, e1a), pa2 = pow_z(d1, e2a), pa3 = pow_z(d1, e3a);
    float pb1 = pow_z(d2, e1b), pb2 = pow_z(d2, e2b), pb3 = pow_z(d2, e3b);
    coeff[g] = make_float4(m2a * pa2, pa3, m2b * pb2, pb3);
    wself[g] = m1a * pa1 + m2a * pa2 * pa3 + m3a
             + m1b * pb1 + m2b * pb2 * pb3 + m3b;
}

// ---------------- exclusive scan of degrees -> rowptr ----------------
__global__ void scan_block_kernel(const int* __restrict__ degi, int* __restrict__ rowptr,
                                  int* __restrict__ blocksum, int n) {
    __shared__ int sums[256];
    int tid = threadIdx.x;
    int base = blockIdx.x * 1024 + tid * 4;
    int d0 = (base + 0 < n) ? degi[base + 0] : 0;
    int d1 = (base + 1 < n) ? degi[base + 1] : 0;
    int d2 = (base + 2 < n) ? degi[base + 2] : 0;
    int d3 = (base + 3 < n) ? degi[base + 3] : 0;
    int s0 = d0, s1 = s0 + d1, s2 = s1 + d2, s3 = s2 + d3;
    sums[tid] = s3;
    __syncthreads();
    for (int off = 1; off < 256; off <<= 1) {
        int v = (tid >= off) ? sums[tid - off] : 0;
        __syncthreads();
        sums[tid] += v;
        __syncthreads();
    }
    int excl = sums[tid] - s3;
    if (base + 0 < n) rowptr[base + 1] = excl + s0;
    if (base + 1 < n) rowptr[base + 2] = excl + s1;
    if (base + 2 < n) rowptr[base + 3] = excl + s2;
    if (base + 3 < n) rowptr[base + 4] = excl + s3;
    if (tid == 255) blocksum[blockIdx.x] = sums[255];
}

__global__ void scan_tops_kernel(const int* __restrict__ blocksum, int* __restrict__ blockoff, int nb) {
    __shared__ int s[128];
    int tid = threadIdx.x;
    int v = (tid < nb) ? blocksum[tid] : 0;
    s[tid] = v;
    __syncthreads();
    for (int off = 1; off < 128; off <<= 1) {
        int u = (tid >= off) ? s[tid - off] : 0;
        __syncthreads();
        s[tid] += u;
        __syncthreads();
    }
    if (tid < nb) blockoff[tid] = s[tid] - v;
}

__global__ void scan_add_kernel(int* __restrict__ rowptr, const int* __restrict__ blockoff, int n) {
    int g = blockIdx.x * blockDim.x + threadIdx.x;
    if (g == 0) rowptr[0] = 0;
    if (g < n) rowptr[g + 1] += blockoff[g >> 10];
}

// ---------------- CSR fill: packed {col, wedge} scatter, 2 edges/thread ----------------
__global__ void fill_edges_kernel(const int* __restrict__ row, const int* __restrict__ col,
                                  const int* __restrict__ rowptr, int* __restrict__ cursor,
                                  const float4* __restrict__ coeff, int2* __restrict__ epack,
                                  int E) {
    int g = (blockIdx.x * blockDim.x + threadIdx.x) * 2;
#pragma unroll
    for (int u = 0; u < 2; ++u) {
        int e = g + u;
        if (e < E) {
            int r = row[e], c = col[e];
            int pos = rowptr[r] + atomicAdd(&cursor[r], 1);
            float4 cr = coeff[r], cc = coeff[c];
            float w = cr.x * cc.y + cr.z * cc.w;
            epack[pos] = make_int2(c, __float_as_int(w));
        }
    }
}

// ---------------- W convert + transpose: Wt[n][k] = (half)W[k][n] ----------------
__global__ void convert_w_kernel(const float* __restrict__ W, _Float16* __restrict__ Wt,
                                 int K, int Nc) {
    int g = blockIdx.x * blockDim.x + threadIdx.x;
    if (g >= K * Nc) return;
    int k = g / Nc, n = g % Nc;
    Wt[(size_t)n * K + k] = (_Float16)W[g];
}

// ---------------- MFMA GEMM: A[n x 128] @ W[128 x TN] -> C[n x TN] fp16 ----------------
// 256 threads (4 waves), 64-row tile, full K=128 in LDS, v_mfma_f32_16x16x32_f16.
template<int TN, typename AT>
__global__ __launch_bounds__(256) void gemm_mfma(const AT* __restrict__ A,
        const _Float16* __restrict__ Wt,   // [TN][128] pre-transposed fp16
        _Float16* __restrict__ C, int n) {
    constexpr int K = 128;
    constexpr int TM = 64;
    constexpr int LDK = K + 8;             // pad 8 halves (16B): bank-stride 4 -> 2-way max
    __shared__ _Float16 As[TM][LDK];
    __shared__ _Float16 Bs[TN][LDK];

    int tid = threadIdx.x;
    int wave = tid >> 6, lane = tid & 63;
    int q = lane >> 4, t = lane & 15;
    int rowbase = blockIdx.x * TM;

    // stage A (convert fp32 -> fp16 if needed)
    if constexpr (std::is_same<AT, float>::value) {
        for (int i = tid; i < TM * K / 4; i += 256) {
            int r = i >> 5;                 // 32 float4 per row
            int kc = (i & 31) * 4;
            int rr = rowbase + r;
            float4 v = make_float4(0.f, 0.f, 0.f, 0.f);
            if (rr < n) v = *(const float4*)&A[(size_t)rr * K + kc];
            As[r][kc + 0] = (_Float16)v.x;
            As[r][kc + 1] = (_Float16)v.y;
            As[r][kc + 2] = (_Float16)v.z;
            As[r][kc + 3] = (_Float16)v.w;
        }
    } else {
        for (int i = tid; i < TM * K / 8; i += 256) {
            int r = i >> 4;                 // 16 x 8-half chunks per row
            int kc = (i & 15) * 8;
            int rr = rowbase + r;
            uint4 v = make_uint4(0u, 0u, 0u, 0u);
            if (rr < n) v = *(const uint4*)&A[(size_t)rr * K + kc];
            *(uint4*)&As[r][kc] = v;        // 272B row stride is 16B-multiple
        }
    }
    // stage Wt
    for (int i = tid; i < TN * K / 8; i += 256) {
        int nr = i >> 4;
        int kc = (i & 15) * 8;
        *(uint4*)&Bs[nr][kc] = *(const uint4*)&Wt[(size_t)nr * K + kc];
    }
    __syncthreads();

    int m0 = wave * 16;
    floatx4 acc[TN / 16];
#pragma unroll
    for (int nt = 0; nt < TN / 16; ++nt) acc[nt] = (floatx4){0.f, 0.f, 0.f, 0.f};

#pragma unroll
    for (int kk = 0; kk < K; kk += 32) {
        half8 a = *(const half8*)&As[m0 + t][kk + q * 8];
#pragma unroll
        for (int nt = 0; nt < TN / 16; ++nt) {
            half8 b = *(const half8*)&Bs[nt * 16 + t][kk + q * 8];
            acc[nt] = __builtin_amdgcn_mfma_f32_16x16x32_f16(a, b, acc[nt], 0, 0, 0);
        }
    }

    // epilogue: C/D layout col=lane&15, row=(lane>>4)*4+reg
#pragma unroll
    for (int nt = 0; nt < TN / 16; ++nt) {
#pragma unroll
        for (int r = 0; r < 4; ++r) {
            int rr = rowbase + m0 + q * 4 + r;
            if (rr < n) C[(size_t)rr * TN + nt * 16 + t] = (_Float16)acc[nt][r];
        }
    }
}

// ---------------- CSR aggregation, D=128, fp16 in / fp16 out, relu ----------------
// One node per wave; lane l holds features [2l,2l+1]; 8 edges in flight.
__global__ __launch_bounds__(256) void agg128_kernel(const __half2* __restrict__ H,
        const int* __restrict__ rowptr, const int2* __restrict__ epack,
        const float* __restrict__ wself, const float* __restrict__ bias,
        __half2* __restrict__ out, int n) {
    int node = blockIdx.x * 4 + (threadIdx.x >> 6);
    if (node >= n) return;
    int lane = threadIdx.x & 63;
    int start = rowptr[node], end = rowptr[node + 1];
    float ws = wself[node];
    float2 hs = __half22float2(H[(size_t)node * 64 + lane]);
    float ax = ws * hs.x, ay = ws * hs.y;
    int e = start;
    for (; e + 8 <= end; e += 8) {
        int2 p0 = epack[e + 0], p1 = epack[e + 1], p2 = epack[e + 2], p3 = epack[e + 3];
        int2 p4 = epack[e + 4], p5 = epack[e + 5], p6 = epack[e + 6], p7 = epack[e + 7];
        __half2 h0 = H[(size_t)p0.x * 64 + lane];
        __half2 h1 = H[(size_t)p1.x * 64 + lane];
        __half2 h2 = H[(size_t)p2.x * 64 + lane];
        __half2 h3 = H[(size_t)p3.x * 64 + lane];
        __half2 h4 = H[(size_t)p4.x * 64 + lane];
        __half2 h5 = H[(size_t)p5.x * 64 + lane];
        __half2 h6 = H[(size_t)p6.x * 64 + lane];
        __half2 h7 = H[(size_t)p7.x * 64 + lane];
        float2 f0 = __half22float2(h0), f1 = __half22float2(h1);
        float2 f2 = __half22float2(h2), f3 = __half22float2(h3);
        float2 f4 = __half22float2(h4), f5 = __half22float2(h5);
        float2 f6 = __half22float2(h6), f7 = __half22float2(h7);
        float w0 = __int_as_float(p0.y), w1 = __int_as_float(p1.y);
        float w2 = __int_as_float(p2.y), w3 = __int_as_float(p3.y);
        float w4 = __int_as_float(p4.y), w5 = __int_as_float(p5.y);
        float w6 = __int_as_float(p6.y), w7 = __int_as_float(p7.y);
        ax += w0 * f0.x + w1 * f1.x + w2 * f2.x + w3 * f3.x
            + w4 * f4.x + w5 * f5.x + w6 * f6.x + w7 * f7.x;
        ay += w0 * f0.y + w1 * f1.y + w2 * f2.y + w3 * f3.y
            + w4 * f4.y + w5 * f5.y + w6 * f6.y + w7 * f7.y;
    }
    for (; e < end; ++e) {
        int2 pe = epack[e];
        float w = __int_as_float(pe.y);
        float2 f = __half22float2(H[(size_t)pe.x * 64 + lane]);
        ax += w * f.x; ay += w * f.y;
    }
    float2 b = *(const float2*)&bias[2 * lane];
    float vx = fmaxf(ax + b.x, 0.0f);
    float vy = fmaxf(ay + b.y, 0.0f);
    out[(size_t)node * 64 + lane] = __floats2half2_rn(vx, vy);
}

// ---------------- CSR aggregation, D=64, fp16 in / fp32 out, no relu ----------------
__global__ __launch_bounds__(256) void agg64_kernel(const __half* __restrict__ H,
        const int* __restrict__ rowptr, const int2* __restrict__ epack,
        const float* __restrict__ wself, const float* __restrict__ bias,
        float* __restrict__ out, int n) {
    int node = blockIdx.x * 4 + (threadIdx.x >> 6);
    if (node >= n) return;
    int lane = threadIdx.x & 63;
    int start = rowptr[node], end = rowptr[node + 1];
    float ws = wself[node];
    float acc = ws * __half2float(H[(size_t)node * 64 + lane]);
    int e = start;
    for (; e + 8 <= end; e += 8) {
        int2 p0 = epack[e + 0], p1 = epack[e + 1], p2 = epack[e + 2], p3 = epack[e + 3];
        int2 p4 = epack[e + 4], p5 = epack[e + 5], p6 = epack[e + 6], p7 = epack[e + 7];
        float f0 = __half2float(H[(size_t)p0.x * 64 + lane]);
        float f1 = __half2float(H[(size_t)p1.x * 64 + lane]);
        float f2 = __half2float(H[(size_t)p2.x * 64 + lane]);
        float f3 = __half2float(H[(size_t)p3.x * 64 + lane]);
        float f4 = __half2float(H[(size_t)p4.x * 64 + lane]);
        float f5 = __half2float(H[(size_t)p5.x * 64 + lane]);
        float f6 = __half2float(H[(size_t)p6.x * 64 + lane]);
        float f7 = __half2float(H[(size_t)p7.x * 64 + lane]);
        acc += __int_as_float(p0.y) * f0 + __int_as_float(p1.y) * f1
             + __int_as_float(p2.y) * f2 + __int_as_float(p3.y) * f3
             + __int_as_float(p4.y) * f4 + __int_as_float(p5.y) * f5
             + __int_as_float(p6.y) * f6 + __int_as_float(p7.y) * f7;
    }
    for (; e < end; ++e) {
        int2 pe = epack[e];
        acc += __int_as_float(pe.y) * __half2float(H[(size_t)pe.x * 64 + lane]);
    }
    out[(size_t)node * 64 + lane] = acc + bias[lane];
}

// ---------------- launch ----------------
extern "C" void kernel_launch(void* const* d_in, const int* in_sizes, int n_in,
                              void* d_out, int out_size, void* d_ws, size_t ws_size,
                              hipStream_t stream) {
    const float* x  = (const float*)d_in[0];
    const int*   ei = (const int*)d_in[1];
    const float* W1 = (const float*)d_in[2];
    const float* b1 = (const float*)d_in[3];
    const float* W2 = (const float*)d_in[4];
    const float* b2 = (const float*)d_in[5];
    const float* W3 = (const float*)d_in[6];
    const float* b3 = (const float*)d_in[7];
    const float* p1 = (const float*)d_in[8];
    const float* p2 = (const float*)d_in[9];

    const int N = in_sizes[0] / 128;
    const int E = in_sizes[1] / 2;
    const int* row = ei;
    const int* col = ei + E;

    char* p = (char*)d_ws;
    auto alloc = [&](size_t bytes) -> void* {
        void* q = (void*)p;
        p += (bytes + 255) & ~(size_t)255;
        return q;
    };
    int*      degi     = (int*)alloc((size_t)N * 4);
    int*      cursor   = (int*)alloc((size_t)N * 4);     // contiguous with degi for one memset
    int*      rowptr   = (int*)alloc((size_t)(N + 1) * 4);
    const int NBLK     = (N + 1023) / 1024;              // 98 for N=100000
    int*      blocksum = (int*)alloc((size_t)NBLK * 4);
    int*      blockoff = (int*)alloc((size_t)NBLK * 4);
    float4*   coeff    = (float4*)alloc((size_t)N * 16);
    float*    wself    = (float*)alloc((size_t)N * 4);
    int2*     epack    = (int2*)alloc((size_t)E * 8);
    _Float16* Wt1      = (_Float16*)alloc(128 * 128 * 2);
    _Float16* Wt2      = (_Float16*)alloc(128 * 128 * 2);
    _Float16* Wt3      = (_Float16*)alloc(128 * 64 * 2);
    _Float16* bufH     = (_Float16*)alloc((size_t)N * 128 * 2);  // GEMM out / gather src
    _Float16* actH     = (_Float16*)alloc((size_t)N * 128 * 2);  // agg out / next GEMM in
    (void)ws_size; (void)n_in;

    size_t zero_bytes = (size_t)((char*)rowptr - (char*)degi);
    hipMemsetAsync(degi, 0, zero_bytes, stream);

    convert_w_kernel<<<(128 * 128 + 255) / 256, 256, 0, stream>>>(W1, Wt1, 128, 128);
    convert_w_kernel<<<(128 * 128 + 255) / 256, 256, 0, stream>>>(W2, Wt2, 128, 128);
    convert_w_kernel<<<(128 * 64 + 255) / 256, 256, 0, stream>>>(W3, Wt3, 128, 64);

    deg_count_kernel<<<(E + 255) / 256, 256, 0, stream>>>(row, degi, E);
    node_coeff_kernel<<<(N + 255) / 256, 256, 0, stream>>>(degi, p1, p2, coeff, wself, N);
    scan_block_kernel<<<NBLK, 256, 0, stream>>>(degi, rowptr, blocksum, N);
    scan_tops_kernel<<<1, 128, 0, stream>>>(blocksum, blockoff, NBLK);
    scan_add_kernel<<<(N + 255) / 256, 256, 0, stream>>>(rowptr, blockoff, N);
    fill_edges_kernel<<<(E / 2 + 255) / 256, 256, 0, stream>>>(row, col, rowptr, cursor,
                                                               coeff, epack, E);

    float* out = (float*)d_out;
    int aggGrid = (N + 3) / 4;
    int gemmGrid = (N + 63) / 64;
    // layer 1
    gemm_mfma<128, float><<<gemmGrid, 256, 0, stream>>>(x, Wt1, bufH, N);
    agg128_kernel<<<aggGrid, 256, 0, stream>>>((const __half2*)bufH, rowptr, epack, wself,
                                               b1, (__half2*)actH, N);
    // layer 2
    gemm_mfma<128, _Float16><<<gemmGrid, 256, 0, stream>>>(actH, Wt2, bufH, N);
    agg128_kernel<<<aggGrid, 256, 0, stream>>>((const __half2*)bufH, rowptr, epack, wself,
                                               b2, (__half2*)actH, N);
    // layer 3 (D_OUT=64, no relu)
    gemm_mfma<64, _Float16><<<gemmGrid, 256, 0, stream>>>(actH, Wt3, bufH, N);
    agg64_kernel<<<aggGrid, 256, 0, stream>>>((const __half*)bufH, rowptr, epack, wself,
                                              b3, out, N);
}